// Round 3
// baseline (25.783 us; speedup 1.0000x reference)
//
#include <hip/hip_runtime.h>
#include <stdint.h>

#define NCFG 96
#define GROUPS 8
#define CFG_PER_G 12
#define CELL_BLOCKS 250          // 64000 / 256
#define NPART (CELL_BLOCKS * GROUPS)

namespace ct {

// ---------------- compile-time numpy RandomState(0) replica ----------------
struct Tabs {
  int topo2tri[NCFG];
  int e0[NCFG][4];
  int e1[NCFG][4];
  int e2[NCFG][4];
  int ntri[NCFG];
  int order[NCFG];   // configs sorted by topo2tri column (stable)
};

struct MT {
  uint32_t mt[624];
  int pos;
  constexpr MT() : mt{}, pos(624) {
    // numpy mt19937_seed(0) == init_genrand(0)
    uint32_t s = 0u;
    for (int i = 0; i < 624; ++i) {
      mt[i] = s;
      s = 1812433253u * (s ^ (s >> 30)) + (uint32_t)(i + 1);
    }
  }
  constexpr uint32_t next() {
    if (pos >= 624) {
      for (int i = 0; i < 624; ++i) {
        uint32_t y = (mt[i] & 0x80000000u) |
                     (mt[(i + 1) == 624 ? 0 : (i + 1)] & 0x7fffffffu);
        uint32_t v = mt[(i + 397) >= 624 ? (i + 397 - 624) : (i + 397)] ^ (y >> 1);
        if (y & 1u) v ^= 0x9908b0dfu;
        mt[i] = v;
      }
      pos = 0;
    }
    uint32_t y = mt[pos++];
    y ^= y >> 11;
    y ^= (y << 7) & 0x9d2c5680u;
    y ^= (y << 15) & 0xefc60000u;
    y ^= y >> 18;
    return y;
  }
};

constexpr Tabs make_tabs() {
  Tabs t{};
  MT g{};
  // TOPO2TRI = randint(0, 256, 96): masked draw, mask=255, never rejects
  for (int i = 0; i < NCFG; ++i) t.topo2tri[i] = (int)(g.next() & 255u);
  // TRI_EDGES = rand(96,4,12).argsort(-1)[..., :3]
  // rk_double = (a*2^26 + b)/2^53, a=next()>>5, b=next()>>6 ; key=(a<<26)|b is
  // order-isomorphic to the double (ties impossible a.s.)
  for (int c = 0; c < NCFG; ++c) {
    for (int tr = 0; tr < 4; ++tr) {
      uint64_t key[12] = {};
      for (int k = 0; k < 12; ++k) {
        uint64_t a = (uint64_t)(g.next() >> 5);
        uint64_t b = (uint64_t)(g.next() >> 6);
        key[k] = (a << 26) | b;
      }
      bool used[12] = {};
      int sel[3] = {};
      for (int s = 0; s < 3; ++s) {
        int best = -1;
        for (int k = 0; k < 12; ++k)
          if (!used[k] && (best < 0 || key[k] < key[best])) best = k;
        used[best] = true;
        sel[s] = best;
      }
      t.e0[c][tr] = sel[0];
      t.e1[c][tr] = sel[1];
      t.e2[c][tr] = sel[2];
    }
  }
  // _NTRI = randint(1, 5, 96): 1 + (draw & 3), never rejects
  for (int c = 0; c < NCFG; ++c) t.ntri[c] = 1 + (int)(g.next() & 3u);
  // stable insertion sort of configs by column (for load dedup / L1 locality)
  for (int i = 0; i < NCFG; ++i) t.order[i] = i;
  for (int i = 1; i < NCFG; ++i) {
    int v = t.order[i];
    int j = i - 1;
    while (j >= 0 && t.topo2tri[t.order[j]] > t.topo2tri[v]) {
      t.order[j + 1] = t.order[j];
      --j;
    }
    t.order[j + 1] = v;
  }
  return t;
}

constexpr Tabs TAB = make_tabs();

// EDGES = [(dx,dy,dz,ax) x 12]
constexpr int EDX[12] = {0,0,0,0, 0,1,0,1, 0,1,0,1};
constexpr int EDY[12] = {0,1,0,1, 0,0,0,0, 0,0,1,1};
constexpr int EDZ[12] = {0,0,1,1, 0,0,1,1, 0,0,0,0};
constexpr int EAX[12] = {0,0,0,0, 1,1,1,1, 2,2,2,2};

} // namespace ct

// ---------------- device math, fully unrolled via templates ----------------

template<int C, int T>
__device__ __forceinline__ void tri_n(const float (&o)[12], float (&n)[3], float& s) {
  constexpr int ea = ct::TAB.e0[C][T];
  constexpr int eb = ct::TAB.e1[C][T];
  constexpr int ec = ct::TAB.e2[C][T];
  // cell base cancels in vertex differences: only corner diffs + off terms remain
  float d1[3] = { (float)(ct::EDX[eb] - ct::EDX[ea]),
                  (float)(ct::EDY[eb] - ct::EDY[ea]),
                  (float)(ct::EDZ[eb] - ct::EDZ[ea]) };
  float d2[3] = { (float)(ct::EDX[ec] - ct::EDX[ea]),
                  (float)(ct::EDY[ec] - ct::EDY[ea]),
                  (float)(ct::EDZ[ec] - ct::EDZ[ea]) };
  d1[ct::EAX[eb]] += o[eb];
  d1[ct::EAX[ea]] -= o[ea];
  d2[ct::EAX[ec]] += o[ec];
  d2[ct::EAX[ea]] -= o[ea];
  n[0] = d1[1] * d2[2] - d1[2] * d2[1];
  n[1] = d1[2] * d2[0] - d1[0] * d2[2];
  n[2] = d1[0] * d2[1] - d1[1] * d2[0];
  s = __builtin_amdgcn_sqrtf(n[0]*n[0] + n[1]*n[1] + n[2]*n[2]) + 1e-8f;
}

__device__ __forceinline__ float pair_term(const float (&a)[3], float sa,
                                           const float (&b)[3], float sb) {
  float d = a[0]*b[0] + a[1]*b[1] + a[2]*b[2];
  return 1.0f - d * __builtin_amdgcn_rcpf(sa * sb);
}

template<int C>
__device__ __forceinline__ float config_curv(const float (&o)[12]) {
  constexpr int NT = ct::TAB.ntri[C];   // >= 2 when called
  float n0[3], n1[3], n2[3], n3[3];
  float s0 = 0.f, s1 = 0.f, s2 = 0.f, s3 = 0.f;
  tri_n<C, 0>(o, n0, s0);
  if constexpr (NT > 1) tri_n<C, 1>(o, n1, s1);
  if constexpr (NT > 2) tri_n<C, 2>(o, n2, s2);
  if constexpr (NT > 3) tri_n<C, 3>(o, n3, s3);
  float curv = 0.0f;
  if constexpr (NT > 1) curv += pair_term(n0, s0, n1, s1);
  if constexpr (NT > 2) curv += pair_term(n1, s1, n2, s2);
  if constexpr (NT > 3) curv += pair_term(n2, s2, n3, s3);
  return curv;
}

// Process configs ORDER[GB .. GB+CFG_PER_G), deduping consecutive equal topo
// columns (one load+FMA per column run). NZ tracks whether the carried curv
// sum is known-nonzero (ntri==1 configs contribute exactly 0 and are skipped).
template<int GB, int I, bool NZ>
__device__ __forceinline__ void do_configs(const float (&o)[12],
                                           const float* __restrict__ topoRow,
                                           float& acc, float carry) {
  if constexpr (I < CFG_PER_G) {
    constexpr int c   = ct::TAB.order[GB + I];
    constexpr int col = ct::TAB.topo2tri[c];
    constexpr bool has = (ct::TAB.ntri[c] > 1);
    float nc = carry;
    if constexpr (has) nc += config_curv<c>(o);
    constexpr bool nz = NZ || has;
    constexpr int nextIdx = (I + 1 < CFG_PER_G) ? (GB + I + 1) : 0; // clamped, unused when flushing at end
    constexpr bool flush = (I + 1 == CFG_PER_G) ||
                           (ct::TAB.topo2tri[ct::TAB.order[nextIdx]] != col);
    if constexpr (flush) {
      if constexpr (nz) acc += topoRow[col] * nc;
      do_configs<GB, I + 1, false>(o, topoRow, acc, 0.0f);
    } else {
      do_configs<GB, I + 1, nz>(o, topoRow, acc, nc);
    }
  }
}

__global__ __launch_bounds__(256)
void curv_kernel(const float* __restrict__ off, const float* __restrict__ topo,
                 float* __restrict__ partials) {
  const int cb = blockIdx.x % CELL_BLOCKS;
  const int g  = blockIdx.x / CELL_BLOCKS;
  const int cell = cb * 256 + (int)threadIdx.x;
  const int x = cell / 1600;
  const int r = cell - x * 1600;
  const int y = r / 40;
  const int z = r - y * 40;

  // 12 per-cell edge offsets; coalesced (consecutive lanes = consecutive z)
  float o[12];
#pragma unroll
  for (int e = 0; e < 12; ++e) {
    o[e] = off[ct::EAX[e] * 68921 + (x + ct::EDX[e]) * 1681 +
               (y + ct::EDY[e]) * 41 + (z + ct::EDZ[e])];
  }

  const float* topoRow = topo + (size_t)cell * 256;
  float acc = 0.0f;
  switch (g) {
    case 0: do_configs< 0, 0, false>(o, topoRow, acc, 0.0f); break;
    case 1: do_configs<12, 0, false>(o, topoRow, acc, 0.0f); break;
    case 2: do_configs<24, 0, false>(o, topoRow, acc, 0.0f); break;
    case 3: do_configs<36, 0, false>(o, topoRow, acc, 0.0f); break;
    case 4: do_configs<48, 0, false>(o, topoRow, acc, 0.0f); break;
    case 5: do_configs<60, 0, false>(o, topoRow, acc, 0.0f); break;
    case 6: do_configs<72, 0, false>(o, topoRow, acc, 0.0f); break;
    default: do_configs<84, 0, false>(o, topoRow, acc, 0.0f); break;
  }

  // wave reduce (64 lanes), then block reduce 4 waves
#pragma unroll
  for (int d = 32; d > 0; d >>= 1) acc += __shfl_down(acc, d, 64);
  __shared__ float wsum[4];
  const int lane = threadIdx.x & 63;
  const int w = threadIdx.x >> 6;
  if (lane == 0) wsum[w] = acc;
  __syncthreads();
  if (threadIdx.x == 0)
    partials[blockIdx.x] = wsum[0] + wsum[1] + wsum[2] + wsum[3];
}

__global__ __launch_bounds__(256)
void reduce_kernel(const float* __restrict__ partials, float* __restrict__ out) {
  float s = 0.0f;
  for (int i = threadIdx.x; i < NPART; i += 256) s += partials[i];
#pragma unroll
  for (int d = 32; d > 0; d >>= 1) s += __shfl_down(s, d, 64);
  __shared__ float wsum[4];
  const int lane = threadIdx.x & 63;
  const int w = threadIdx.x >> 6;
  if (lane == 0) wsum[w] = s;
  __syncthreads();
  if (threadIdx.x == 0) out[0] = wsum[0] + wsum[1] + wsum[2] + wsum[3];
}

extern "C" void kernel_launch(void* const* d_in, const int* in_sizes, int n_in,
                              void* d_out, int out_size, void* d_ws, size_t ws_size,
                              hipStream_t stream) {
  const float* off  = (const float*)d_in[0];   // [3, 41, 41, 41] f32
  const float* topo = (const float*)d_in[1];   // [64000, 256] f32
  float* out = (float*)d_out;                  // scalar f32
  float* partials = (float*)d_ws;              // NPART floats

  curv_kernel<<<dim3(NPART), dim3(256), 0, stream>>>(off, topo, partials);
  reduce_kernel<<<dim3(1), dim3(256), 0, stream>>>(partials, out);
}